// Round 4
// baseline (888.101 us; speedup 1.0000x reference)
//
#include <hip/hip_runtime.h>
#include <hip/hip_bf16.h>

// ---------------- problem constants ----------------
#define BATCH 16
#define CI    512
#define CO    512
#define IMG   64
#define HP    66
#define NPIX  4096
#define NTAP  9

typedef __bf16  bf16x8  __attribute__((ext_vector_type(8)));
typedef float   floatx4 __attribute__((ext_vector_type(4)));

// ---------------- workspace layout (bytes) ----------------
#define OFF_S     0u
#define OFF_SIG   32768u
#define OFF_WSQ   65536u
#define OFF_WBF   1114112u
#define OFF_XPAD  5832704u
#define XPAD_BYTES 71368704u
#define WS_NEEDED (OFF_XPAD + XPAD_BYTES)

// ---------------- prep: s = style @ (affine_w/sqrt(512)).T + affine_b ----------------
__global__ void k_style(const float* __restrict__ style, const float* __restrict__ aw,
                        const float* __restrict__ ab, float* __restrict__ s_out)
{
    __shared__ float st[512];
    int b = blockIdx.x;
    int t = threadIdx.x;
    st[t]       = style[b * 512 + t];
    st[t + 256] = style[b * 512 + t + 256];
    __syncthreads();
    int i = blockIdx.y * 256 + t;
    const float4* awr = (const float4*)(aw + (size_t)i * 512);
    float sum = 0.f;
#pragma unroll 8
    for (int k = 0; k < 128; ++k) {
        float4 v = awr[k];
        sum += v.x * st[4 * k] + v.y * st[4 * k + 1] + v.z * st[4 * k + 2] + v.w * st[4 * k + 3];
    }
    s_out[b * 512 + i] = sum * 0.04419417382415922f + ab[i];
}

// ---------------- prep: wsq[o,i] = sum_t w^2, wbf[tap][o][ci] = bf16(w) ----------------
__global__ void k_wprep(const float* __restrict__ wgt, float* __restrict__ wsq,
                        unsigned short* __restrict__ wbf)
{
    __shared__ float sw[2304];
    int t = threadIdx.x;
    int blk = blockIdx.x;
    const float4* src = (const float4*)(wgt + (size_t)blk * 2304);
#pragma unroll
    for (int k = 0; k < 2; ++k) ((float4*)sw)[t + 256 * k] = src[t + 256 * k];
    if (t < 64) ((float4*)sw)[t + 512] = src[t + 512];
    __syncthreads();

    int idx = blk * 256 + t;
    const float* p = sw + t * 9;
    float q = 0.f;
#pragma unroll
    for (int t9 = 0; t9 < 9; ++t9) {
        float v = p[t9];
        q += v * v;
        __hip_bfloat16 hv = __float2bfloat16(v);
        wbf[t9 * 262144 + idx] = *(unsigned short*)&hv;
    }
    wsq[idx] = q;
}

// ---------------- prep: sigma_inv[b,o] = rsqrt(sum_i wsq[o,i]*s[b,i]^2 + eps) ----------------
__global__ void k_sigma(const float* __restrict__ s_in, const float* __restrict__ wsq,
                        float* __restrict__ sig)
{
    __shared__ float s2[512];
    int b = blockIdx.x, t = threadIdx.x;
    float a0 = s_in[b * 512 + t], a1 = s_in[b * 512 + t + 256];
    s2[t] = a0 * a0;
    s2[t + 256] = a1 * a1;
    __syncthreads();
    int o = blockIdx.y * 256 + t;
    const float4* wr = (const float4*)(wsq + (size_t)o * 512);
    float sum = 0.f;
#pragma unroll 8
    for (int k = 0; k < 128; ++k) {
        float4 v = wr[k];
        sum += v.x * s2[4 * k] + v.y * s2[4 * k + 1] + v.z * s2[4 * k + 2] + v.w * s2[4 * k + 3];
    }
    sig[b * 512 + o] = rsqrtf(sum + 1e-8f);
}

// ---------------- prep: xpad NHWC bf16 modulate + halo, 128-ci slices ----------------
__global__ void k_xmod(const float* __restrict__ x, const float* __restrict__ s_in,
                       unsigned short* __restrict__ xpad)
{
    __shared__ unsigned short tile[64 * 128];   // 16 KB
    __shared__ float sm_s[128];
    int b = blockIdx.x, h = blockIdx.y, quarter = blockIdx.z;
    int ci0 = quarter << 7;
    int t = threadIdx.x;
    if (t < 128) sm_s[t] = s_in[b * 512 + ci0 + t];
    __syncthreads();

    int w0 = (t & 15) << 2;
    int cp = (t >> 4) << 1;
#pragma unroll
    for (int i = 0; i < 4; ++i) {
        int cl = (i << 5) + cp;
        float sv0 = sm_s[cl], sv1 = sm_s[cl + 1];
        float4 v0 = *(const float4*)(x + (((size_t)(b * 512 + ci0 + cl)) << 12) + (h << 6) + w0);
        float4 v1 = *(const float4*)(x + (((size_t)(b * 512 + ci0 + cl + 1)) << 12) + (h << 6) + w0);
        float a0[4] = {v0.x, v0.y, v0.z, v0.w};
        float a1[4] = {v1.x, v1.y, v1.z, v1.w};
#pragma unroll
        for (int j = 0; j < 4; ++j) {
            int wq = w0 + j;
            __hip_bfloat16 h0 = __float2bfloat16(a0[j] * sv0);
            __hip_bfloat16 h1 = __float2bfloat16(a1[j] * sv1);
            unsigned int packed = (unsigned int)(*(unsigned short*)&h0)
                                | ((unsigned int)(*(unsigned short*)&h1) << 16);
            int off = (wq << 7) + ((((cl >> 3) ^ ((wq >> 2) & 7))) << 3) + (cl & 7);
            *(unsigned int*)&tile[off] = packed;
        }
    }
    __syncthreads();

    int q = t & 15;
    size_t rowb = (size_t)((b * 66 + h + 1) * 66 + 1) * 512 + ci0;
#pragma unroll
    for (int i = 0; i < 4; ++i) {
        int wq = (i << 4) + (t >> 4);
        int off = (wq << 7) + ((q ^ ((wq >> 2) & 7)) << 3);
        uint4 v = *(const uint4*)&tile[off];
        *(uint4*)(xpad + rowb + (size_t)wq * 512 + (q << 3)) = v;
    }

    // halo: w=0 / w=65 of this padded row
    uint4 z = {0u, 0u, 0u, 0u};
    if (t < 32) {
        int wp = (t >> 4) * 65;
        *(uint4*)(xpad + (size_t)((b * 66 + h + 1) * 66 + wp) * 512 + ci0 + ((t & 15) << 3)) = z;
    }
    // halo: full padded top/bottom rows
    if (h == 0 || h == 63) {
        int hp = (h == 0) ? 0 : 65;
        size_t base = (size_t)(b * 66 + hp) * 66 * 512 + ci0;
        for (int idx = t; idx < 66 * 16; idx += 256) {
            int p = idx >> 4, c = idx & 15;
            *(uint4*)(xpad + base + (size_t)p * 512 + (c << 3)) = z;
        }
    }
}

// ---------------- main conv: A-direct-to-register implicit GEMM ----------------
// Round-3 diagnosis: LDS read BW bound (192 KB reads + 66 KB writes per CU-step =
// ~2600-3000 cyc vs 1862 matrix cyc; MfmaUtil 46%). Fix: weights (A) bypass LDS —
// each wave global-loads its 12 MFMA A-fragments directly into registers
// (16 rows x 64 B pattern, L1/L2-hot, shared by 512 blocks). LDS now holds only
// the pixel strip B (6x reuse: 3 kw x 2 wr-waves). A-regs double-buffered via
// even/odd unrolled loop (static indexing). LDS: 66 KB -> 16.9 KB.
__device__ __forceinline__ void gload16(const void* g, void* l)
{
    __builtin_amdgcn_global_load_lds(
        (const __attribute__((address_space(1))) unsigned int*)g,
        (__attribute__((address_space(3))) unsigned int*)l, 16, 0, 0);
}

__global__ __launch_bounds__(256, 2)
void k_conv(const unsigned short* __restrict__ xpad, const unsigned short* __restrict__ wbf,
            const float* __restrict__ sig, float* __restrict__ y)
{
    // B only: 2 x (132 rows x 32 k) swizzled bf16
    __shared__ unsigned short B_lds[2 * 4224];       // 16896 B
    int t = threadIdx.x;
    int w = t >> 6, l = t & 63;
    int wr = w >> 1, wc = w & 1;
    int bx = blockIdx.x;
    int b = bx >> 7, rem = bx & 127;
    int co_t = rem >> 5, pix_t = rem & 31;
    int o_base = co_t << 7;
    int h0 = pix_t << 1;                         // padded row base for kh=0

    const char* wb = (const char*)wbf;
    const char* xb = (const char*)xpad;

    // ---- B staging offsets (per-thread, loop-invariant) ----
    int idx0 = (w << 6) + l;
    int idx1 = idx0 + 256;
    int r0 = idx0 >> 2;                                    // 0..63  (sr=0)
    int bof0 = ((b * 66 + h0) * 66 + r0) * 1024 + (((idx0 & 3) ^ ((r0 >> 1) & 3)) << 4);
    int r1 = idx1 >> 2;                                    // 64..127
    int sr1 = (r1 >= 66) ? 1 : 0;
    int wp1 = r1 - 66 * sr1;
    int bof1 = ((b * 66 + h0 + sr1) * 66 + wp1) * 1024 + (((idx1 & 3) ^ ((r1 >> 1) & 3)) << 4);
    int idxt = 512 + (w << 2) + l;                         // tail (lanes l<4)
    int rt = 128 + w;                                      // sr=1, wp=62+w
    int boft = ((b * 66 + h0 + 1) * 66 + 62 + w) * 1024 + (((idxt & 3) ^ ((rt >> 1) & 3)) << 4);

    // ---- fragment offsets ----
    int lr = l & 15, q = l >> 4;
    // A-direct per-lane base: row = o_base + wr*64 + lr, k-slice q (16 B)
    const char* pA = wb + (((size_t)(o_base + wr * 64 + lr)) << 10) + (q << 4);
    int fbo[3][4];
#pragma unroll
    for (int kw = 0; kw < 3; ++kw)
#pragma unroll
        for (int j = 0; j < 4; ++j) {
            int sp = wc * 66 + j * 16 + lr + kw;
            fbo[kw][j] = sp * 32 + ((q ^ ((sp >> 1) & 3)) << 3);
        }

    floatx4 acc[4][4];
#pragma unroll
    for (int i = 0; i < 4; ++i)
#pragma unroll
        for (int j = 0; j < 4; ++j)
            acc[i][j] = (floatx4){0.f, 0.f, 0.f, 0.f};

    bf16x8 A0[12], A1[12];

    // stage B strip for step (kh = step/16, cic = step%16) into LDS buffer nb
    auto stageB = [&](int step, int nb) {
        int kh = step >> 4;
        int cic = step & 15;
        const char* xk = xb + kh * 67584 + (cic << 6);     // kh * 66 rows * 1 KB
        char* bbase = (char*)(B_lds + nb * 4224);
        gload16(xk + bof0, bbase + (w << 10));
        gload16(xk + bof1, bbase + 4096 + (w << 10));
        if (l < 4) gload16(xk + boft, bbase + ((512 + (w << 2)) << 4));
    };

    // load the 12 A fragments (3 kw x 4 i) for step directly into registers
    auto loadA = [&](int step, bf16x8 (&Ad)[12]) {
        int kh = step >> 4;
        int cic = step & 15;
        const char* base = pA + kh * 1572864 + (cic << 6);
#pragma unroll
        for (int kw = 0; kw < 3; ++kw)
#pragma unroll
            for (int i = 0; i < 4; ++i)
                Ad[kw * 4 + i] = *(const bf16x8*)(base + kw * 524288 + i * 16384);
    };

    auto compute = [&](const unsigned short* Bb, const bf16x8 (&A)[12]) {
#pragma unroll
        for (int kw = 0; kw < 3; ++kw) {
            bf16x8 bfr[4];
#pragma unroll
            for (int j = 0; j < 4; ++j) bfr[j] = *(const bf16x8*)&Bb[fbo[kw][j]];
#pragma unroll
            for (int i = 0; i < 4; ++i)
#pragma unroll
                for (int j = 0; j < 4; ++j)
                    acc[i][j] = __builtin_amdgcn_mfma_f32_16x16x32_bf16(A[kw * 4 + i], bfr[j], acc[i][j], 0, 0, 0);
        }
    };

    // ---- prologue: stage step 0 (buffer 0, A0) ----
    stageB(0, 0);
    loadA(0, A0);
    asm volatile("s_waitcnt vmcnt(0)" ::: "memory");
    __builtin_amdgcn_s_barrier();
    __builtin_amdgcn_sched_barrier(0);

    // 48 steps, even/odd unrolled (static A-buffer indexing)
    for (int s2 = 0; s2 < 24; ++s2) {
        int e = s2 * 2;
        // even: compute(buf0, A0), prefetch step e+1 -> buf1/A1
        stageB(e + 1, 1);
        loadA(e + 1, A1);
        compute(B_lds, A0);
        asm volatile("s_waitcnt vmcnt(0) lgkmcnt(0)" ::: "memory");
        __builtin_amdgcn_s_barrier();
        __builtin_amdgcn_sched_barrier(0);
        // odd: compute(buf1, A1), prefetch step e+2 -> buf0/A0
        if (e + 2 < 48) {
            stageB(e + 2, 0);
            loadA(e + 2, A0);
        }
        compute(B_lds + 4224, A1);
        asm volatile("s_waitcnt vmcnt(0) lgkmcnt(0)" ::: "memory");
        __builtin_amdgcn_s_barrier();
        __builtin_amdgcn_sched_barrier(0);
    }

    // epilogue: C/D layout col=lane&15 (pixel), row=quad*4+reg (co)
    int col = l & 15, quad = l >> 4;
    const float* sb = sig + b * 512;
#pragma unroll
    for (int i = 0; i < 4; ++i) {
        int ob = o_base + wr * 64 + i * 16 + quad * 4;
#pragma unroll
        for (int r = 0; r < 4; ++r) {
            int o = ob + r;
            float sv = sb[o];
            float* yrow = y + (((size_t)(b * 512 + o)) << 12);
#pragma unroll
            for (int j = 0; j < 4; ++j) {
                int pix = (pix_t << 7) + wc * 64 + j * 16 + col;
                yrow[pix] = acc[i][j][r] * sv;
            }
        }
    }
}

// ---------------- launcher ----------------
extern "C" void kernel_launch(void* const* d_in, const int* in_sizes, int n_in,
                              void* d_out, int out_size, void* d_ws, size_t ws_size,
                              hipStream_t stream)
{
    const float* x        = (const float*)d_in[0];
    const float* style    = (const float*)d_in[1];
    const float* weight   = (const float*)d_in[2];
    const float* affine_w = (const float*)d_in[3];
    const float* affine_b = (const float*)d_in[4];
    float* y = (float*)d_out;

    if (ws_size < (size_t)WS_NEEDED) return;

    char* ws = (char*)d_ws;
    float*          s_buf = (float*)(ws + OFF_S);
    float*          sig   = (float*)(ws + OFF_SIG);
    float*          wsq   = (float*)(ws + OFF_WSQ);
    unsigned short* wbf   = (unsigned short*)(ws + OFF_WBF);
    unsigned short* xpad  = (unsigned short*)(ws + OFF_XPAD);

    k_style<<<dim3(16, 2), 256, 0, stream>>>(style, affine_w, affine_b, s_buf);
    k_wprep<<<1024, 256, 0, stream>>>(weight, wsq, wbf);
    k_xmod<<<dim3(16, 64, 4), 256, 0, stream>>>(x, s_buf, xpad);
    k_sigma<<<dim3(16, 2), 256, 0, stream>>>(s_buf, wsq, sig);
    k_conv<<<2048, 256, 0, stream>>>(xpad, wbf, sig, y);
}

// Round 7
// 522.858 us; speedup vs baseline: 1.6986x; 1.6986x over previous
//
#include <hip/hip_runtime.h>
#include <hip/hip_bf16.h>

// ---------------- problem constants ----------------
#define BATCH 16
#define CI    512
#define CO    512
#define IMG   64
#define HP    66
#define NPIX  4096
#define NTAP  9

typedef __bf16  bf16x8  __attribute__((ext_vector_type(8)));
typedef float   floatx4 __attribute__((ext_vector_type(4)));

// ---------------- workspace layout (bytes) ----------------
#define OFF_S     0u
#define OFF_SIG   32768u
#define OFF_WSQ   65536u
#define OFF_WBF   1114112u
#define OFF_XPAD  5832704u
#define XPAD_BYTES 71368704u
#define WS_NEEDED (OFF_XPAD + XPAD_BYTES)

// ---------------- prep: s = style @ (affine_w/sqrt(512)).T + affine_b ----------------
__global__ void k_style(const float* __restrict__ style, const float* __restrict__ aw,
                        const float* __restrict__ ab, float* __restrict__ s_out)
{
    __shared__ float st[512];
    int b = blockIdx.x;
    int t = threadIdx.x;
    st[t]       = style[b * 512 + t];
    st[t + 256] = style[b * 512 + t + 256];
    __syncthreads();
    int i = blockIdx.y * 256 + t;
    const float4* awr = (const float4*)(aw + (size_t)i * 512);
    float sum = 0.f;
#pragma unroll 8
    for (int k = 0; k < 128; ++k) {
        float4 v = awr[k];
        sum += v.x * st[4 * k] + v.y * st[4 * k + 1] + v.z * st[4 * k + 2] + v.w * st[4 * k + 3];
    }
    s_out[b * 512 + i] = sum * 0.04419417382415922f + ab[i];
}

// ---------------- prep: wsq[o,i] = sum_t w^2, wbf[tap][o][ci] = bf16(w) ----------------
__global__ void k_wprep(const float* __restrict__ wgt, float* __restrict__ wsq,
                        unsigned short* __restrict__ wbf)
{
    __shared__ float sw[2304];
    int t = threadIdx.x;
    int blk = blockIdx.x;
    const float4* src = (const float4*)(wgt + (size_t)blk * 2304);
#pragma unroll
    for (int k = 0; k < 2; ++k) ((float4*)sw)[t + 256 * k] = src[t + 256 * k];
    if (t < 64) ((float4*)sw)[t + 512] = src[t + 512];
    __syncthreads();

    int idx = blk * 256 + t;
    const float* p = sw + t * 9;
    float q = 0.f;
#pragma unroll
    for (int t9 = 0; t9 < 9; ++t9) {
        float v = p[t9];
        q += v * v;
        __hip_bfloat16 hv = __float2bfloat16(v);
        wbf[t9 * 262144 + idx] = *(unsigned short*)&hv;
    }
    wsq[idx] = q;
}

// ---------------- prep: sigma_inv[b,o] = rsqrt(sum_i wsq[o,i]*s[b,i]^2 + eps) ----------------
__global__ void k_sigma(const float* __restrict__ s_in, const float* __restrict__ wsq,
                        float* __restrict__ sig)
{
    __shared__ float s2[512];
    int b = blockIdx.x, t = threadIdx.x;
    float a0 = s_in[b * 512 + t], a1 = s_in[b * 512 + t + 256];
    s2[t] = a0 * a0;
    s2[t + 256] = a1 * a1;
    __syncthreads();
    int o = blockIdx.y * 256 + t;
    const float4* wr = (const float4*)(wsq + (size_t)o * 512);
    float sum = 0.f;
#pragma unroll 8
    for (int k = 0; k < 128; ++k) {
        float4 v = wr[k];
        sum += v.x * s2[4 * k] + v.y * s2[4 * k + 1] + v.z * s2[4 * k + 2] + v.w * s2[4 * k + 3];
    }
    sig[b * 512 + o] = rsqrtf(sum + 1e-8f);
}

// ---------------- prep: xpad NHWC bf16 modulate + halo, 128-ci slices ----------------
__global__ void k_xmod(const float* __restrict__ x, const float* __restrict__ s_in,
                       unsigned short* __restrict__ xpad)
{
    __shared__ unsigned short tile[64 * 128];   // 16 KB
    __shared__ float sm_s[128];
    int b = blockIdx.x, h = blockIdx.y, quarter = blockIdx.z;
    int ci0 = quarter << 7;
    int t = threadIdx.x;
    if (t < 128) sm_s[t] = s_in[b * 512 + ci0 + t];
    __syncthreads();

    int w0 = (t & 15) << 2;
    int cp = (t >> 4) << 1;
#pragma unroll
    for (int i = 0; i < 4; ++i) {
        int cl = (i << 5) + cp;
        float sv0 = sm_s[cl], sv1 = sm_s[cl + 1];
        float4 v0 = *(const float4*)(x + (((size_t)(b * 512 + ci0 + cl)) << 12) + (h << 6) + w0);
        float4 v1 = *(const float4*)(x + (((size_t)(b * 512 + ci0 + cl + 1)) << 12) + (h << 6) + w0);
        float a0[4] = {v0.x, v0.y, v0.z, v0.w};
        float a1[4] = {v1.x, v1.y, v1.z, v1.w};
#pragma unroll
        for (int j = 0; j < 4; ++j) {
            int wq = w0 + j;
            __hip_bfloat16 h0 = __float2bfloat16(a0[j] * sv0);
            __hip_bfloat16 h1 = __float2bfloat16(a1[j] * sv1);
            unsigned int packed = (unsigned int)(*(unsigned short*)&h0)
                                | ((unsigned int)(*(unsigned short*)&h1) << 16);
            int off = (wq << 7) + ((((cl >> 3) ^ ((wq >> 2) & 7))) << 3) + (cl & 7);
            *(unsigned int*)&tile[off] = packed;
        }
    }
    __syncthreads();

    int q = t & 15;
    size_t rowb = (size_t)((b * 66 + h + 1) * 66 + 1) * 512 + ci0;
#pragma unroll
    for (int i = 0; i < 4; ++i) {
        int wq = (i << 4) + (t >> 4);
        int off = (wq << 7) + ((q ^ ((wq >> 2) & 7)) << 3);
        uint4 v = *(const uint4*)&tile[off];
        *(uint4*)(xpad + rowb + (size_t)wq * 512 + (q << 3)) = v;
    }

    // halo: w=0 / w=65 of this padded row
    uint4 z = {0u, 0u, 0u, 0u};
    if (t < 32) {
        int wp = (t >> 4) * 65;
        *(uint4*)(xpad + (size_t)((b * 66 + h + 1) * 66 + wp) * 512 + ci0 + ((t & 15) << 3)) = z;
    }
    // halo: full padded top/bottom rows
    if (h == 0 || h == 63) {
        int hp = (h == 0) ? 0 : 65;
        size_t base = (size_t)(b * 66 + hp) * 66 * 512 + ci0;
        for (int idx = t; idx < 66 * 16; idx += 256) {
            int p = idx >> 4, c = idx & 15;
            *(uint4*)(xpad + base + (size_t)p * 512 + (c << 3)) = z;
        }
    }
}

// ---------------- main conv: 128co x 256px block, 64x128 wave tiles ----------------
// Round-4 diagnosis: LDS-port bound. Wave tile 64x128 cuts fragment reads/FLOP to
// 0.75x. B stores PACKED rows (64 cols/img-row, no pad cols) so LDS = exactly 80 KiB
// -> 2 blocks/CU. Boundary taps (c=0,kw=0)/(c=63,kw=2) zeroed in-register.
// Counted vmcnt(10) (T4): barriers never drain the in-flight stage.
__device__ __forceinline__ void gload16(const void* g, void* l)
{
    __builtin_amdgcn_global_load_lds(
        (const __attribute__((address_space(1))) unsigned int*)g,
        (__attribute__((address_space(3))) unsigned int*)l, 16, 0, 0);
}

__global__ __launch_bounds__(256, 2)
void k_conv(const unsigned short* __restrict__ xpad, const unsigned short* __restrict__ wbf,
            const float* __restrict__ sig, float* __restrict__ y)
{
    // A: 2 buf x 3 kw x [128 o][32 k] swizzled = 49152 B
    // B: 2 buf x [256 packed rows][32 k] swizzled = 32768 B   (total 81920 B)
    __shared__ unsigned short A_lds[24576];
    __shared__ unsigned short B_lds[16384];
    int t = threadIdx.x;
    int w = t >> 6, l = t & 63;
    int wr = w >> 1, wc = w & 1;
    int bx = blockIdx.x;
    int b = bx >> 6, rem = bx & 63;
    int co_t = rem >> 4, pxt = rem & 15;
    int o_base = co_t << 7;
    int h0 = pxt << 2;                           // 4 image rows per block

    const char* wb = (const char*)wbf;
    const char* xb = (const char*)xpad;

    // ---- staging source offsets (per-thread, loop-invariant) ----
    // A: idx = k*256 + t, k=0..5: kwsect = idx>>9, row = (idx>>2)&127, slot = idx&3
    int aofs[6];
#pragma unroll
    for (int k = 0; k < 6; ++k) {
        int idx = k * 256 + t;
        int kwsect = idx >> 9;
        int row = (idx >> 2) & 127;
        int slot = idx & 3;
        aofs[k] = kwsect * 524288 + (o_base + row) * 1024 + ((slot ^ ((row >> 1) & 3)) << 4);
    }
    // B: idx = k*256 + t, k=0..3: row = idx>>2 (packed: ir*64+cp), slot = idx&3
    int bofs[4];
#pragma unroll
    for (int k = 0; k < 4; ++k) {
        int idx = k * 256 + t;
        int row = idx >> 2;
        int ir = row >> 6, cp = row & 63;
        int slot = idx & 3;
        bofs[k] = ((b * 66 + h0 + ir) * 66 + (cp + 1)) * 1024 + ((slot ^ ((row >> 1) & 3)) << 4);
    }

    // ---- fragment offsets (shorts, loop-invariant) ----
    int lr = l & 15, q = l >> 4;
    int fa = wr * 2048 + lr * 32 + ((q ^ ((lr >> 1) & 3)) << 3);
    int fbo[3][8];
#pragma unroll
    for (int kw = 0; kw < 3; ++kw)
#pragma unroll
        for (int j = 0; j < 8; ++j) {
            int ir = wc * 2 + (j >> 2);
            int cp = (j & 3) * 16 + lr + kw - 1;
            int cpc = cp < 0 ? 0 : (cp > 63 ? 63 : cp);
            int row = ir * 64 + cpc;
            fbo[kw][j] = row * 32 + ((q ^ ((row >> 1) & 3)) << 3);
        }
    bool m_lo = (lr == 0);    // masks (c=0,kw=0) fragments j=0,4
    bool m_hi = (lr == 15);   // masks (c=63,kw=2) fragments j=3,7

    floatx4 acc[4][8];
#pragma unroll
    for (int i = 0; i < 4; ++i)
#pragma unroll
        for (int j = 0; j < 8; ++j)
            acc[i][j] = (floatx4){0.f, 0.f, 0.f, 0.f};

    // stage step (kh = step/16, cic = step%16) into buffer nb: 10 gloads, uniform
    auto stage = [&](int step, int nb) {
        int kh = step >> 4;
        int cic = step & 15;
        const char* wk = wb + kh * 1572864 + (cic << 6);
        const char* xk = xb + kh * 67584 + (cic << 6);
        char* aL = (char*)A_lds + nb * 24576 + (w << 10);
        char* bL = (char*)B_lds + nb * 16384 + (w << 10);
#pragma unroll
        for (int k = 0; k < 6; ++k) gload16(wk + aofs[k], aL + k * 4096);
#pragma unroll
        for (int k = 0; k < 4; ++k) gload16(xk + bofs[k], bL + k * 4096);
    };

    bf16x8 bz = {};
    auto compute = [&](const unsigned short* Ab, const unsigned short* Bb) {
#pragma unroll
        for (int kw = 0; kw < 3; ++kw) {
            bf16x8 bfr[8], af[4];
#pragma unroll
            for (int j = 0; j < 8; ++j) bfr[j] = *(const bf16x8*)&Bb[fbo[kw][j]];
            if (kw == 0) { if (m_lo) { bfr[0] = bz; bfr[4] = bz; } }
            if (kw == 2) { if (m_hi) { bfr[3] = bz; bfr[7] = bz; } }
#pragma unroll
            for (int i = 0; i < 4; ++i) af[i] = *(const bf16x8*)&Ab[kw * 4096 + fa + i * 512];
#pragma unroll
            for (int i = 0; i < 4; ++i)
#pragma unroll
                for (int j = 0; j < 8; ++j)
                    acc[i][j] = __builtin_amdgcn_mfma_f32_16x16x32_bf16(af[i], bfr[j], acc[i][j], 0, 0, 0);
        }
    };

    const unsigned short* A0 = A_lds;
    const unsigned short* A1 = A_lds + 12288;
    const unsigned short* B0 = B_lds;
    const unsigned short* B1 = B_lds + 8192;

    // ---- prologue: two stages in flight, wait only for the first ----
    stage(0, 0);
    stage(1, 1);
    asm volatile("s_waitcnt vmcnt(10)" ::: "memory");
    __builtin_amdgcn_s_barrier();
    __builtin_amdgcn_sched_barrier(0);

    // steps 0..45 (paired for static buffer indexing)
    for (int s2 = 0; s2 < 23; ++s2) {
        int e = s2 * 2;
        // even step e: read buf0
        compute(A0, B0);
        __builtin_amdgcn_s_barrier();            // all waves done reading buf0
        __builtin_amdgcn_sched_barrier(0);
        stage(e + 2, 0);                         // overwrite buf0 for step e+2
        asm volatile("s_waitcnt vmcnt(10)" ::: "memory");   // stage(e+1) landed
        __builtin_amdgcn_s_barrier();            // publish buf1
        __builtin_amdgcn_sched_barrier(0);
        // odd step e+1: read buf1
        compute(A1, B1);
        __builtin_amdgcn_s_barrier();
        __builtin_amdgcn_sched_barrier(0);
        stage(e + 3, 1);
        asm volatile("s_waitcnt vmcnt(10)" ::: "memory");   // stage(e+2) landed
        __builtin_amdgcn_s_barrier();
        __builtin_amdgcn_sched_barrier(0);
    }
    // step 46 (buf0): no more staging; drain stage(47) fully
    compute(A0, B0);
    __builtin_amdgcn_s_barrier();
    __builtin_amdgcn_sched_barrier(0);
    asm volatile("s_waitcnt vmcnt(0)" ::: "memory");
    __builtin_amdgcn_s_barrier();
    __builtin_amdgcn_sched_barrier(0);
    // step 47 (buf1)
    compute(A1, B1);

    // epilogue: C/D layout col=lane&15 (pixel), row=quad*4+reg (co)
    int col = lr, quad = q;
    const float* sb = sig + b * 512;
#pragma unroll
    for (int i = 0; i < 4; ++i) {
        int ob = o_base + wr * 64 + i * 16 + quad * 4;
#pragma unroll
        for (int r = 0; r < 4; ++r) {
            int o = ob + r;
            float sv = sb[o];
            float* yrow = y + (((size_t)(b * 512 + o)) << 12);
#pragma unroll
            for (int j = 0; j < 8; ++j) {
                int pix = (pxt << 8) + wc * 128 + j * 16 + col;
                yrow[pix] = acc[i][j][r] * sv;
            }
        }
    }
}

// ---------------- launcher ----------------
extern "C" void kernel_launch(void* const* d_in, const int* in_sizes, int n_in,
                              void* d_out, int out_size, void* d_ws, size_t ws_size,
                              hipStream_t stream)
{
    const float* x        = (const float*)d_in[0];
    const float* style    = (const float*)d_in[1];
    const float* weight   = (const float*)d_in[2];
    const float* affine_w = (const float*)d_in[3];
    const float* affine_b = (const float*)d_in[4];
    float* y = (float*)d_out;

    if (ws_size < (size_t)WS_NEEDED) return;

    char* ws = (char*)d_ws;
    float*          s_buf = (float*)(ws + OFF_S);
    float*          sig   = (float*)(ws + OFF_SIG);
    float*          wsq   = (float*)(ws + OFF_WSQ);
    unsigned short* wbf   = (unsigned short*)(ws + OFF_WBF);
    unsigned short* xpad  = (unsigned short*)(ws + OFF_XPAD);

    k_style<<<dim3(16, 2), 256, 0, stream>>>(style, affine_w, affine_b, s_buf);
    k_wprep<<<1024, 256, 0, stream>>>(weight, wsq, wbf);
    k_xmod<<<dim3(16, 64, 4), 256, 0, stream>>>(x, s_buf, xpad);
    k_sigma<<<dim3(16, 2), 256, 0, stream>>>(s_buf, wsq, sig);
    k_conv<<<1024, 256, 0, stream>>>(xpad, wbf, sig, y);
}